// Round 1
// baseline (9.832 us; speedup 1.0000x reference)
//
#include <hip/hip_runtime.h>

// Net: opp-LSTM (zero initial state) + 10 fused gen-LSTM cells + 2-layer decode.
// Tiny problem (~60K FLOPs, ~86KB live bytes) -> single block, single kernel,
// latency-bound. W_hh_opp is dead (h0=0) and never read.

__device__ __forceinline__ float fsigmoid(float v) {
    return 1.0f / (1.0f + __expf(-v));
}
__device__ __forceinline__ float ftanh(float v) {
    float e = __expf(2.0f * v);
    return (e - 1.0f) / (e + 1.0f);
}

__global__ __launch_bounds__(256) void net_kernel(
    const float* __restrict__ x,          // (8)
    const float* __restrict__ h0_gen,     // (10,10)
    const float* __restrict__ c0_gen,     // (10,10)
    const float* __restrict__ W_ih_opp,   // (200,8)
    const float* __restrict__ b_ih_opp,   // (200)
    const float* __restrict__ b_hh_opp,   // (200)
    const float* __restrict__ W_ih_gen,   // (10,40,8)
    const float* __restrict__ W_hh_gen,   // (10,40,10)
    const float* __restrict__ b_ih_gen,   // (10,40)
    const float* __restrict__ b_hh_gen,   // (10,40)
    const float* __restrict__ W1,         // (75,150)
    const float* __restrict__ b1,         // (75)
    const float* __restrict__ W2,         // (1,75)
    const float* __restrict__ b2,         // (1)
    float* __restrict__ out)              // (1)
{
    __shared__ float xs[8];
    __shared__ float h0s[100];
    __shared__ float gates_opp[200];
    __shared__ float gates_gen[400];
    __shared__ float feat[150];   // [0:100]=h_gen flat, [100:150]=h_opp
    __shared__ float part[150];   // W1 row partial sums (2 halves per row)

    const int t = threadIdx.x;

    if (t < 8)   xs[t]  = x[t];
    if (t < 100) h0s[t] = h0_gen[t];
    __syncthreads();

    // ---- opp gates: gates = Wih@x + bih + bhh   (Whh@h == 0 since h0 = 0)
    if (t < 200) {
        float g = b_ih_opp[t] + b_hh_opp[t];
        #pragma unroll
        for (int k = 0; k < 8; ++k) g += W_ih_opp[t * 8 + k] * xs[k];
        gates_opp[t] = g;
    }
    // ---- gen gates: 10 cells x 40 gates, each = 8-dot(x) + 10-dot(h0) + biases
    for (int u = t; u < 400; u += 256) {
        float g = b_ih_gen[u] + b_hh_gen[u];
        #pragma unroll
        for (int k = 0; k < 8; ++k) g += W_ih_gen[u * 8 + k] * xs[k];
        const int cell = u / 40;
        #pragma unroll
        for (int h = 0; h < 10; ++h) g += W_hh_gen[u * 10 + h] * h0s[cell * 10 + h];
        gates_gen[u] = g;
    }
    __syncthreads();

    // ---- activations (PyTorch gate order i,f,g,o)
    if (t < 100) {                      // gen cells -> feat[0:100]
        const int g = t / 10, j = t % 10;
        const int base = g * 40 + j;
        const float ig = fsigmoid(gates_gen[base]);
        const float fg = fsigmoid(gates_gen[base + 10]);
        const float gg = ftanh(gates_gen[base + 20]);
        const float og = fsigmoid(gates_gen[base + 30]);
        const float c  = fg * c0_gen[t] + ig * gg;
        feat[t] = og * ftanh(c);
    } else if (t >= 128 && t < 178) {   // opp cell -> feat[100:150] (other waves)
        const int j = t - 128;
        const float ig = fsigmoid(gates_opp[j]);
        const float gg = ftanh(gates_opp[100 + j]);
        const float og = fsigmoid(gates_opp[150 + j]);
        const float c  = ig * gg;       // f-gate * c0 vanishes (c0 = 0)
        feat[100 + j] = og * ftanh(c);
    }
    __syncthreads();

    // ---- y1 = W1 @ feat + b1 : 2 threads per row, 75 MACs each
    if (t < 150) {
        const int r = t >> 1, half = t & 1;
        const float* wrow = W1 + r * 150 + half * 75;
        const float* frow = feat + half * 75;
        float s = 0.0f;
        #pragma unroll 5
        for (int k = 0; k < 75; ++k) s += wrow[k] * frow[k];
        part[t] = s;
    }
    __syncthreads();

    // ---- out = W2 @ y1 + b2 : wave-0 shuffle reduction over 75 terms
    if (t < 64) {
        float s = 0.0f;
        for (int idx = t; idx < 75; idx += 64)
            s += W2[idx] * (part[2 * idx] + part[2 * idx + 1] + b1[idx]);
        #pragma unroll
        for (int off = 32; off > 0; off >>= 1)
            s += __shfl_down(s, off);
        if (t == 0) out[0] = s + b2[0];
    }
}

extern "C" void kernel_launch(void* const* d_in, const int* in_sizes, int n_in,
                              void* d_out, int out_size, void* d_ws, size_t ws_size,
                              hipStream_t stream) {
    const float* x        = (const float*)d_in[0];
    const float* h0_gen   = (const float*)d_in[1];
    const float* c0_gen   = (const float*)d_in[2];
    const float* W_ih_opp = (const float*)d_in[3];
    // d_in[4] = W_hh_opp -- dead (opp LSTM runs from zero state)
    const float* b_ih_opp = (const float*)d_in[5];
    const float* b_hh_opp = (const float*)d_in[6];
    const float* W_ih_gen = (const float*)d_in[7];
    const float* W_hh_gen = (const float*)d_in[8];
    const float* b_ih_gen = (const float*)d_in[9];
    const float* b_hh_gen = (const float*)d_in[10];
    const float* W1       = (const float*)d_in[11];
    const float* b1       = (const float*)d_in[12];
    const float* W2       = (const float*)d_in[13];
    const float* b2       = (const float*)d_in[14];
    float* out = (float*)d_out;

    net_kernel<<<1, 256, 0, stream>>>(x, h0_gen, c0_gen,
                                      W_ih_opp, b_ih_opp, b_hh_opp,
                                      W_ih_gen, W_hh_gen, b_ih_gen, b_hh_gen,
                                      W1, b1, W2, b2, out);
}

// Round 2
// 9.710 us; speedup vs baseline: 1.0125x; 1.0125x over previous
//
#include <hip/hip_runtime.h>

// Net: opp-LSTM (zero initial state) + 10 fused gen-LSTM cells + 2-layer decode.
// ~60K FLOPs, ~86KB live bytes -> single block, single kernel, latency-bound.
// W_hh_opp is dead (h0=0). Structure: 2 barriers total.
//   Phase A: waves 0-1 -> gen cells fused (gates+activations per element),
//            wave 2   -> opp cell fused. feat[150] in LDS.
//   Phase B: W1 matvec, 3 threads/row (50 MACs each), W2[r] and b1[r] folded in.
//   Phase C: wave-0 shuffle reduction -> out.

__device__ __forceinline__ float fsigmoid(float v) {
    return 1.0f / (1.0f + __expf(-v));
}
__device__ __forceinline__ float ftanh(float v) {
    float e = __expf(2.0f * v);
    return (e - 1.0f) / (e + 1.0f);
}

__global__ __launch_bounds__(256) void net_kernel(
    const float* __restrict__ x,          // (8)
    const float* __restrict__ h0_gen,     // (10,10)
    const float* __restrict__ c0_gen,     // (10,10)
    const float* __restrict__ W_ih_opp,   // (200,8)
    const float* __restrict__ b_ih_opp,   // (200)
    const float* __restrict__ b_hh_opp,   // (200)
    const float* __restrict__ W_ih_gen,   // (10,40,8)
    const float* __restrict__ W_hh_gen,   // (10,40,10)
    const float* __restrict__ b_ih_gen,   // (10,40)
    const float* __restrict__ b_hh_gen,   // (10,40)
    const float* __restrict__ W1,         // (75,150)
    const float* __restrict__ b1,         // (75)
    const float* __restrict__ W2,         // (1,75)
    const float* __restrict__ b2,         // (1)
    float* __restrict__ out)              // (1)
{
    __shared__ float feat[152];   // [0:100]=h_gen flat, [100:150]=h_opp
    __shared__ float part[256];   // W2[r] * (W1-row-chunk dot + b1 fold)

    const int t = threadIdx.x;

    // ---- Phase A: fused gates + activations, no staging barrier ----
    if (t < 100) {
        // gen cell element: cell = t/10, j = t%10
        const int cell = t / 10;
        const int j = t - cell * 10;

        const float4 x0 = ((const float4*)x)[0];
        const float4 x1 = ((const float4*)x)[1];
        const float xv[8] = {x0.x, x0.y, x0.z, x0.w, x1.x, x1.y, x1.z, x1.w};

        float hv[10];
        const float2* h2 = (const float2*)(h0_gen + cell * 10);
        #pragma unroll
        for (int i = 0; i < 5; ++i) { float2 v = h2[i]; hv[2*i] = v.x; hv[2*i+1] = v.y; }

        float gate[4];   // i, f, g, o (PyTorch order: rows +0,+10,+20,+30)
        #pragma unroll
        for (int q = 0; q < 4; ++q) {
            const int row = cell * 40 + q * 10 + j;
            float g = b_ih_gen[row] + b_hh_gen[row];
            const float4* wi = (const float4*)(W_ih_gen + row * 8);
            const float4 a = wi[0], b = wi[1];
            g += a.x*xv[0] + a.y*xv[1] + a.z*xv[2] + a.w*xv[3]
               + b.x*xv[4] + b.y*xv[5] + b.z*xv[6] + b.w*xv[7];
            const float2* wh = (const float2*)(W_hh_gen + row * 10);
            #pragma unroll
            for (int i = 0; i < 5; ++i) { float2 v = wh[i]; g += v.x*hv[2*i] + v.y*hv[2*i+1]; }
            gate[q] = g;
        }
        const float c = fsigmoid(gate[1]) * c0_gen[t] + fsigmoid(gate[0]) * ftanh(gate[2]);
        feat[t] = fsigmoid(gate[3]) * ftanh(c);
    } else if (t >= 128 && t < 178) {
        // opp cell element j on wave 2; c0=h0=0 so only i,g,o gates matter
        const int j = t - 128;

        const float4 x0 = ((const float4*)x)[0];
        const float4 x1 = ((const float4*)x)[1];
        const float xv[8] = {x0.x, x0.y, x0.z, x0.w, x1.x, x1.y, x1.z, x1.w};

        float gate[3];   // i, g, o at rows j, 100+j, 150+j
        const int rows[3] = {j, 100 + j, 150 + j};
        #pragma unroll
        for (int q = 0; q < 3; ++q) {
            const int row = rows[q];
            float g = b_ih_opp[row] + b_hh_opp[row];
            const float4* wi = (const float4*)(W_ih_opp + row * 8);
            const float4 a = wi[0], b = wi[1];
            g += a.x*xv[0] + a.y*xv[1] + a.z*xv[2] + a.w*xv[3]
               + b.x*xv[4] + b.y*xv[5] + b.z*xv[6] + b.w*xv[7];
            gate[q] = g;
        }
        const float c = fsigmoid(gate[0]) * ftanh(gate[1]);   // f*c0 == 0
        feat[100 + j] = fsigmoid(gate[2]) * ftanh(c);
    }
    __syncthreads();

    // ---- Phase B: part[t] = W2[r] * (dot(W1[r, c*50:+50], feat[c*50:+50]) + (c==0)*b1[r])
    if (t < 225) {
        const int r = t / 3;
        const int c = t - r * 3;
        const float2* wp = (const float2*)(W1 + r * 150 + c * 50);
        const float2* fp = (const float2*)(feat + c * 50);
        float s = (c == 0) ? b1[r] : 0.0f;
        #pragma unroll
        for (int i = 0; i < 25; ++i) {
            const float2 wv = wp[i], fv = fp[i];
            s += wv.x * fv.x + wv.y * fv.y;
        }
        part[t] = W2[r] * s;
    } else {
        part[t] = 0.0f;
    }
    __syncthreads();

    // ---- Phase C: 256 -> 1 reduction on wave 0
    if (t < 64) {
        float s = part[t] + part[t + 64] + part[t + 128] + part[t + 192];
        #pragma unroll
        for (int off = 32; off > 0; off >>= 1)
            s += __shfl_down(s, off);
        if (t == 0) out[0] = s + b2[0];
    }
}

extern "C" void kernel_launch(void* const* d_in, const int* in_sizes, int n_in,
                              void* d_out, int out_size, void* d_ws, size_t ws_size,
                              hipStream_t stream) {
    const float* x        = (const float*)d_in[0];
    const float* h0_gen   = (const float*)d_in[1];
    const float* c0_gen   = (const float*)d_in[2];
    const float* W_ih_opp = (const float*)d_in[3];
    // d_in[4] = W_hh_opp -- dead (opp LSTM runs from zero state)
    const float* b_ih_opp = (const float*)d_in[5];
    const float* b_hh_opp = (const float*)d_in[6];
    const float* W_ih_gen = (const float*)d_in[7];
    const float* W_hh_gen = (const float*)d_in[8];
    const float* b_ih_gen = (const float*)d_in[9];
    const float* b_hh_gen = (const float*)d_in[10];
    const float* W1       = (const float*)d_in[11];
    const float* b1       = (const float*)d_in[12];
    const float* W2       = (const float*)d_in[13];
    const float* b2       = (const float*)d_in[14];
    float* out = (float*)d_out;

    net_kernel<<<1, 256, 0, stream>>>(x, h0_gen, c0_gen,
                                      W_ih_opp, b_ih_opp, b_hh_opp,
                                      W_ih_gen, W_hh_gen, b_ih_gen, b_hh_gen,
                                      W1, b1, W2, b2, out);
}